// Round 8
// baseline (668.886 us; speedup 1.0000x reference)
//
#include <hip/hip_runtime.h>

// ---------------------------------------------------------------------------
// CombinedModel: 3x relu-LSTM (keypoint) + tanh-LSTM + GRU (img) + heads.
//   KEY r8 change: all in-loop barriers are raw s_barrier with lgkmcnt(0)
//   drain ONLY (no vmcnt drain) -> global prefetches float across barriers.
//   __syncthreads() drains vmcnt(0), which was serializing both the LSTM
//   per-step xz prefetch and the GEMM's pipelined B/A loads.
//   LSTMs: xz prefetch depth 2 (covers ~900cyc HBM latency across 2 steps).
// ---------------------------------------------------------------------------

typedef short bf16x8 __attribute__((ext_vector_type(8)));
typedef float f32x4 __attribute__((ext_vector_type(4)));

__device__ __forceinline__ void block_sync_lds() {
    asm volatile("s_waitcnt lgkmcnt(0)" ::: "memory");   // LDS visible
    __builtin_amdgcn_s_barrier();                        // no vmcnt drain
    __builtin_amdgcn_sched_barrier(0);                   // no hoisting across
}

__device__ __forceinline__ unsigned f2bf(float x) {
    unsigned u = __float_as_uint(x);
    return (u + 0x7FFFu + ((u >> 16) & 1u)) >> 16;   // RNE; inputs finite
}
__device__ __forceinline__ float bf2f(unsigned b) { return __uint_as_float(b << 16); }
__device__ __forceinline__ float sigmoidf_(float x) { return 1.f / (1.f + __expf(-x)); }
__device__ __forceinline__ float tanhf_(float x) {
    float e = __expf(2.f * x);
    return 1.f - 2.f / (e + 1.f);
}

// 2 fp32 -> packed bf16 hi pair + packed bf16 lo pair (HW RNE; validated absmax 0.0).
__device__ __forceinline__ void cvt2(float x0, float x1, unsigned& hp, unsigned& lp) {
    unsigned h;
    asm("v_cvt_pk_bf16_f32 %0, %1, %2" : "=v"(h) : "v"(x0), "v"(x1));
    float a0 = __uint_as_float(h << 16);
    float a1 = __uint_as_float(h & 0xffff0000u);
    unsigned l;
    asm("v_cvt_pk_bf16_f32 %0, %1, %2" : "=v"(l) : "v"(x0 - a0), "v"(x1 - a1));
    hp = h; lp = l;
}

// ---------------------------------------------------------------------------
// Weight pre-split: W[K,N] f32 -> bf16 hi/lo, blocked [kt][n][32].
// ---------------------------------------------------------------------------
template<int K, int N>
__device__ __forceinline__ void split_w(const float* __restrict__ W,
                                        unsigned short* __restrict__ hi,
                                        unsigned short* __restrict__ lo, int item) {
    int kt = item / N;
    int n  = item % N;
    unsigned uh[16], ul[16];
#pragma unroll
    for (int p = 0; p < 16; p++) {
        unsigned h2[2], l2[2];
#pragma unroll
        for (int e = 0; e < 2; e++) {
            int k = kt * 32 + p * 2 + e;
            float x = (k < K) ? W[(size_t)k * N + n] : 0.f;
            unsigned hb = f2bf(x);
            h2[e] = hb;
            l2[e] = f2bf(x - bf2f(hb));
        }
        uh[p] = h2[0] | (h2[1] << 16);
        ul[p] = l2[0] | (l2[1] << 16);
    }
    size_t off = (size_t)(kt * N + n) * 32;
    uint4* dh = (uint4*)(hi + off);
    uint4* dl = (uint4*)(lo + off);
#pragma unroll
    for (int c = 0; c < 4; c++) {
        uint4 v; v.x = uh[c*4]; v.y = uh[c*4+1]; v.z = uh[c*4+2]; v.w = uh[c*4+3];
        dh[c] = v;
        uint4 u; u.x = ul[c*4]; u.y = ul[c*4+1]; u.z = ul[c*4+2]; u.w = ul[c*4+3];
        dl[c] = u;
    }
}

__global__ __launch_bounds__(256) void split_all(
    const float* kW1x, const float* iWx, const float* kW2x, const float* kW3x,
    unsigned short* w1h, unsigned short* w1l, unsigned short* wih, unsigned short* wil,
    unsigned short* w2h, unsigned short* w2l, unsigned short* w3h, unsigned short* w3l) {
    int wid = blockIdx.x * 256 + threadIdx.x;
    if (wid < 13312)       split_w<1662, 256>(kW1x, w1h, w1l, wid);
    else if (wid < 29696)  split_w<2048, 256>(iWx,  wih, wil, wid - 13312);
    else if (wid < 30720)  split_w<64,   512>(kW2x, w2h, w2l, wid - 29696);
    else if (wid < 31744)  split_w<128,  256>(kW3x, w3h, w3l, wid - 30720);
}

// ---------------------------------------------------------------------------
// GEMM: tile 128m x 128n, 4 waves x (128m x 32n), pipelined; barriers now
// drain LDS only, so loadB(g+1)/loadA(g+2) stay in flight across them.
// ---------------------------------------------------------------------------
__global__ __launch_bounds__(256, 2) void gemm_rd(
    const float* __restrict__ A, const unsigned short* __restrict__ Bhi,
    const unsigned short* __restrict__ Blo, const float* __restrict__ bias,
    float* __restrict__ out0, float* __restrict__ out1,
    int Kreal, int Kt, int Nfull) {
    const int m0  = blockIdx.x * 128;
    const int n0  = blockIdx.y * 128;
    const int ks  = blockIdx.z;
    const int nks = gridDim.z;
    const int ktChunk = Kt / nks;
    const int kt0 = ks * ktChunk;
    const int G   = (ktChunk + 1) / 2;
    const int tid = threadIdx.x;
    const int lane = tid & 63;
    const int wv   = tid >> 6;
    const int l15  = lane & 15;
    const int q    = lane >> 4;
    const int row  = tid >> 1;
    const int kc   = tid & 1;

    __shared__ unsigned short Ah[2][2][128 * 40], Al[2][2][128 * 40];  // 80 KB

    f32x4 acc[8][2];
#pragma unroll
    for (int i = 0; i < 8; i++)
#pragma unroll
        for (int j = 0; j < 2; j++) acc[i][j] = (f32x4){0.f, 0.f, 0.f, 0.f};

    auto loadA = [&](int g, float* r) {
        int kb = (kt0 + 2 * g + kc) * 32;
        const float* ap = A + (size_t)(m0 + row) * Kreal + kb;
        if (kb + 32 <= Kreal) {
#pragma unroll
            for (int j = 0; j < 16; j++) {
                float2 p = *(const float2*)(ap + 2 * j);
                r[2*j] = p.x; r[2*j+1] = p.y;
            }
        } else {
#pragma unroll
            for (int j = 0; j < 16; j++) {
                int gk = kb + 2 * j;
                r[2*j]   = (gk     < Kreal) ? ap[2*j]   : 0.f;
                r[2*j+1] = (gk + 1 < Kreal) ? ap[2*j+1] : 0.f;
            }
        }
    };
    auto writeA = [&](int buf, const float* r) {
        unsigned ph[16], pl[16];
#pragma unroll
        for (int p = 0; p < 16; p++) cvt2(r[2*p], r[2*p+1], ph[p], pl[p]);
        uint4* dh = (uint4*)&Ah[buf][kc][row * 40];
        uint4* dl = (uint4*)&Al[buf][kc][row * 40];
#pragma unroll
        for (int c = 0; c < 4; c++) {
            uint4 v; v.x = ph[c*4]; v.y = ph[c*4+1]; v.z = ph[c*4+2]; v.w = ph[c*4+3];
            dh[c] = v;
            uint4 u; u.x = pl[c*4]; u.y = pl[c*4+1]; u.z = pl[c*4+2]; u.w = pl[c*4+3];
            dl[c] = u;
        }
    };
    auto loadB = [&](int g, bf16x8* bh, bf16x8* bl) {
#pragma unroll
        for (int sub = 0; sub < 2; sub++)
#pragma unroll
            for (int nt = 0; nt < 2; nt++) {
                size_t boff = ((size_t)(kt0 + 2 * g + sub) * Nfull + n0 + wv * 32 + nt * 16 + l15) * 32 + q * 8;
                bh[sub * 2 + nt] = *(const bf16x8*)(Bhi + boff);
                bl[sub * 2 + nt] = *(const bf16x8*)(Blo + boff);
            }
    };
    auto compute = [&](int buf, const bf16x8* bh, const bf16x8* bl) {
#pragma unroll
        for (int sub = 0; sub < 2; sub++)
#pragma unroll
            for (int mt = 0; mt < 8; mt++) {
                int o = (mt * 16 + l15) * 40 + q * 8;
                bf16x8 ah = *(const bf16x8*)&Ah[buf][sub][o];
                bf16x8 al = *(const bf16x8*)&Al[buf][sub][o];
#pragma unroll
                for (int nt = 0; nt < 2; nt++) {
                    acc[mt][nt] = __builtin_amdgcn_mfma_f32_16x16x32_bf16(ah, bh[sub*2+nt], acc[mt][nt], 0, 0, 0);
                    acc[mt][nt] = __builtin_amdgcn_mfma_f32_16x16x32_bf16(ah, bl[sub*2+nt], acc[mt][nt], 0, 0, 0);
                    acc[mt][nt] = __builtin_amdgcn_mfma_f32_16x16x32_bf16(al, bh[sub*2+nt], acc[mt][nt], 0, 0, 0);
                }
            }
    };

    float  rA[32], rB[32];
    bf16x8 bhA[4], blA[4], bhB[4], blB[4];
    loadA(0, rA);
    writeA(0, rA);
    loadB(0, bhA, blA);
    if (G > 1) loadA(1, rB);
    block_sync_lds();

    for (int g = 0; g < G; g += 2) {
        if (g + 1 < G) loadB(g + 1, bhB, blB);
        if (g + 2 < G) loadA(g + 2, rA);
        compute(0, bhA, blA);
        if (g + 1 < G) writeA(1, rB);
        block_sync_lds();
        if (g + 1 < G) {
            if (g + 2 < G) loadB(g + 2, bhA, blA);
            if (g + 3 < G) loadA(g + 3, rB);
            compute(1, bhB, blB);
            if (g + 2 < G) writeA(0, rA);
            block_sync_lds();
        }
    }

    float* op = (ks == 0) ? out0 : out1;
#pragma unroll
    for (int nt = 0; nt < 2; nt++) {
        int gcol = n0 + wv * 32 + nt * 16 + l15;
        float bv = (ks == 0) ? bias[gcol] : 0.f;
#pragma unroll
        for (int mt = 0; mt < 8; mt++)
#pragma unroll
            for (int r = 0; r < 4; r++) {
                int grow = m0 + mt * 16 + q * 4 + r;
                op[(size_t)grow * Nfull + gcol] = acc[mt][nt][r] + bv;
            }
    }
}

// ---------------------------------------------------------------------------
// LSTM H=64, G=256 (dual-config) — ONE LDS-only barrier per step, xz
// prefetch depth 2 (streams kept in separate regs; add at use).
// Optional fused GRU (img branch) on wave 0 from LDS h-history.
// ---------------------------------------------------------------------------
__global__ __launch_bounds__(256) void lstm_h64(
    int nA,
    const float* __restrict__ xA0, const float* __restrict__ xA1,
    const float* __restrict__ WhA, float* __restrict__ hA, int actA,
    const float* __restrict__ xB0, const float* __restrict__ xB1,
    const float* __restrict__ WhB, float* __restrict__ hB, int actB,
    const float* __restrict__ gWx, const float* __restrict__ gWh,
    const float* __restrict__ gb,  float* __restrict__ glast) {
    int bid = blockIdx.x;
    bool sec = bid >= nA;
    int b = sec ? bid - nA : bid;
    const float* x0 = sec ? xB0 : xA0;
    const float* x1 = sec ? xB1 : xA1;
    const float* Wh = sec ? WhB : WhA;
    float* hout     = sec ? hB  : hA;
    int act         = sec ? actB : actA;
    bool has1  = (x1 != nullptr);
    bool fused = sec && (glast != nullptr);

    int g = threadIdx.x;
    int w = g >> 6;
    int l = g & 63;
    float wreg[64];
#pragma unroll
    for (int k = 0; k < 64; k++) wreg[k] = Wh[k * 256 + g];

    __shared__ alignas(16) float hs4[4][64];   // per-wave private h copy
    __shared__ float za[2][256];               // double-buffered gates
    __shared__ alignas(16) float hseq[64][64]; // h history (fused GRU only)
    hs4[w][l] = 0.f;                           // own wave's row: no sync needed
    float c = 0.f;

    const float* x0r = x0 + (size_t)b * 64 * 256;
    const float* x1r = has1 ? x1 + (size_t)b * 64 * 256 : x0r;
    float* hr = hout ? hout + (size_t)b * 64 * 64 : nullptr;
    bool isc = (g >= 128) && (g < 192);
    // depth-2 prefetch, streams separate
    float c0a = x0r[g],                 c0b = has1 ? x1r[g] : 0.f;
    float n1a = x0r[256 + g],           n1b = has1 ? x1r[256 + g] : 0.f;
    for (int t = 0; t < 64; t++) {
        float n2a = 0.f, n2b = 0.f;
        if (t + 2 < 64) {
            n2a = x0r[(t + 2) * 256 + g];
            if (has1) n2b = x1r[(t + 2) * 256 + g];
        }
        float z0 = c0a + c0b, z1 = 0.f, z2 = 0.f, z3 = 0.f;
#pragma unroll
        for (int kk = 0; kk < 16; kk++) {
            float4 h4 = *(const float4*)&hs4[w][kk * 4];
            z0 = fmaf(h4.x, wreg[kk * 4 + 0], z0);
            z1 = fmaf(h4.y, wreg[kk * 4 + 1], z1);
            z2 = fmaf(h4.z, wreg[kk * 4 + 2], z2);
            z3 = fmaf(h4.w, wreg[kk * 4 + 3], z3);
        }
        float z = (z0 + z1) + (z2 + z3);
        float a;
        if (isc) a = (act == 0) ? fmaxf(z, 0.f) : tanhf_(z);
        else     a = sigmoidf_(z);
        int p = t & 1;
        za[p][g] = a;
        block_sync_lds();
        float iv = za[p][l], fv = za[p][64 + l], cd = za[p][128 + l], ov = za[p][192 + l];
        c = fmaf(fv, c, iv * cd);
        float ca = (act == 0) ? fmaxf(c, 0.f) : tanhf_(c);
        float h = ov * ca;
        hs4[w][l] = h;                        // own copy: next read is wave-local
        if (w == 0) {
            if (hr) hr[t * 64 + l] = h;
            if (fused) hseq[t][l] = h;
        }
        c0a = n1a; c0b = n1b; n1a = n2a; n1b = n2b;
    }

    // ---- fused GRU (img branch), wave 0 only; h-seq from LDS broadcast ----
    if (fused && w == 0) {
        int qq = l;
        int col = (qq < 24) ? qq : 0;
        float wx[64], wh[8];
#pragma unroll
        for (int k = 0; k < 64; k++) wx[k] = gWx[k * 24 + col];
#pragma unroll
        for (int k = 0; k < 8; k++)  wh[k] = gWh[k * 24 + col];
        float b0 = gb[col], b1 = gb[24 + col];
        float hval = 0.f;                     // lanes 0..7 hold h state
        for (int t = 0; t < 64; t++) {
            float s0 = b0, s1 = 0.f, s2 = 0.f, s3 = 0.f;
#pragma unroll
            for (int kk = 0; kk < 16; kk++) {
                float4 h4 = *(const float4*)&hseq[t][kk * 4];
                s0 = fmaf(h4.x, wx[kk * 4 + 0], s0);
                s1 = fmaf(h4.y, wx[kk * 4 + 1], s1);
                s2 = fmaf(h4.z, wx[kk * 4 + 2], s2);
                s3 = fmaf(h4.w, wx[kk * 4 + 3], s3);
            }
            float sx = (s0 + s1) + (s2 + s3);
            float sr = b1;
#pragma unroll
            for (int k = 0; k < 8; k++) sr = fmaf(__shfl(hval, k), wh[k], sr);
            float xzz = __shfl(sx, qq),      rzz = __shfl(sr, qq);
            float xzr = __shfl(sx, 8 + qq),  rzr = __shfl(sr, 8 + qq);
            float xzh = __shfl(sx, 16 + qq), rzh = __shfl(sr, 16 + qq);
            float zz = sigmoidf_(xzz + rzz);
            float rv = sigmoidf_(xzr + rzr);
            float hc = tanhf_(xzh + rv * rzh);
            hval = zz * hval + (1.f - zz) * hc;
        }
        if (qq < 8) glast[b * 8 + qq] = hval;
    }
}

// ---------------------------------------------------------------------------
// LSTM H=128, G=512 — ONE LDS-only barrier per step, depth-2 prefetch.
// ---------------------------------------------------------------------------
__global__ __launch_bounds__(512, 2) void lstm_h128(
    const float* __restrict__ xz, const float* __restrict__ Wh, float* __restrict__ hout) {
    int b = blockIdx.x;
    int g = threadIdx.x;
    int w = g >> 6;
    int l = g & 63;
    float wreg[128];
#pragma unroll
    for (int k = 0; k < 128; k++) wreg[k] = Wh[k * 512 + g];

    __shared__ alignas(16) float hs8[8][128];  // per-wave private h copy
    __shared__ float za[2][512];
    hs8[w][l] = 0.f;
    hs8[w][64 + l] = 0.f;
    float c0 = 0.f, c1 = 0.f;

    const float* xzr = xz + (size_t)b * 64 * 512;
    float* hr = hout + (size_t)b * 64 * 128;
    bool isc = (g >= 256) && (g < 384);
    float cur = xzr[g];
    float nx1 = xzr[512 + g];
    for (int t = 0; t < 64; t++) {
        float nx2 = 0.f;
        if (t + 2 < 64) nx2 = xzr[(t + 2) * 512 + g];
        float z0 = cur, z1 = 0.f, z2 = 0.f, z3 = 0.f;
#pragma unroll
        for (int kk = 0; kk < 32; kk++) {
            float4 h4 = *(const float4*)&hs8[w][kk * 4];
            z0 = fmaf(h4.x, wreg[kk * 4 + 0], z0);
            z1 = fmaf(h4.y, wreg[kk * 4 + 1], z1);
            z2 = fmaf(h4.z, wreg[kk * 4 + 2], z2);
            z3 = fmaf(h4.w, wreg[kk * 4 + 3], z3);
        }
        float z = (z0 + z1) + (z2 + z3);
        float a = isc ? fmaxf(z, 0.f) : sigmoidf_(z);
        int p = t & 1;
        za[p][g] = a;
        block_sync_lds();
        {
            float iv = za[p][l],      fv = za[p][128 + l];
            float cd = za[p][256 + l], ov = za[p][384 + l];
            c0 = fmaf(fv, c0, iv * cd);
            float h = ov * fmaxf(c0, 0.f);
            hs8[w][l] = h;
            if (w == 0) hr[t * 128 + l] = h;
        }
        {
            float iv = za[p][64 + l],  fv = za[p][192 + l];
            float cd = za[p][320 + l], ov = za[p][448 + l];
            c1 = fmaf(fv, c1, iv * cd);
            float h = ov * fmaxf(c1, 0.f);
            hs8[w][64 + l] = h;
            if (w == 0) hr[t * 128 + 64 + l] = h;
        }
        cur = nx1; nx1 = nx2;
    }
}

// ---------------------------------------------------------------------------
// Dense heads + concat + final dense + softmax. 4 blocks x 64 rows.
// ---------------------------------------------------------------------------
__global__ __launch_bounds__(64) void final_head(
    const float* __restrict__ h3seq, const float* __restrict__ glast,
    const float* __restrict__ kD1w, const float* __restrict__ kD1b,
    const float* __restrict__ kD2w, const float* __restrict__ kD2b,
    const float* __restrict__ iDw,  const float* __restrict__ iDb,
    const float* __restrict__ fW,   const float* __restrict__ fb,
    float* __restrict__ outp) {
    int b = blockIdx.x * 64 + threadIdx.x;
    float h3[64];
#pragma unroll
    for (int k = 0; k < 64; k++) h3[k] = h3seq[((size_t)b * 64 + 63) * 64 + k];
    float d1[64];
#pragma unroll
    for (int j = 0; j < 64; j++) {
        float s = kD1b[j];
#pragma unroll
        for (int k = 0; k < 64; k++) s = fmaf(h3[k], kD1w[k * 64 + j], s);
        d1[j] = fmaxf(s, 0.f);
    }
    float d2[32];
#pragma unroll
    for (int j = 0; j < 32; j++) {
        float s = kD2b[j];
#pragma unroll
        for (int k = 0; k < 64; k++) s = fmaf(d1[k], kD2w[k * 32 + j], s);
        d2[j] = fmaxf(s, 0.f);
    }
    float gi[8];
#pragma unroll
    for (int k = 0; k < 8; k++) gi[k] = glast[b * 8 + k];
    float io[8];
#pragma unroll
    for (int j = 0; j < 8; j++) {
        float s = iDb[j];
#pragma unroll
        for (int k = 0; k < 8; k++) s = fmaf(gi[k], iDw[k * 8 + j], s);
        io[j] = fmaxf(s, 0.f);
    }
    float lg[10];
#pragma unroll
    for (int j = 0; j < 10; j++) {
        float s = fb[j];
#pragma unroll
        for (int k = 0; k < 8; k++)  s = fmaf(io[k], fW[k * 10 + j], s);
#pragma unroll
        for (int k = 0; k < 32; k++) s = fmaf(d2[k], fW[(8 + k) * 10 + j], s);
        lg[j] = s;
    }
    float mx = lg[0];
#pragma unroll
    for (int j = 1; j < 10; j++) mx = fmaxf(mx, lg[j]);
    float den = 0.f, ex[10];
#pragma unroll
    for (int j = 0; j < 10; j++) { ex[j] = __expf(lg[j] - mx); den += ex[j]; }
    float inv = 1.f / den;
#pragma unroll
    for (int j = 0; j < 10; j++) outp[b * 10 + j] = ex[j] * inv;
}

// ---------------------------------------------------------------------------
extern "C" void kernel_launch(void* const* d_in, const int* in_sizes, int n_in,
                              void* d_out, int out_size, void* d_ws, size_t ws_size,
                              hipStream_t stream) {
    const float* keypoint = (const float*)d_in[0];
    const float* img      = (const float*)d_in[1];
    const float* kW1x = (const float*)d_in[2];
    const float* kW1h = (const float*)d_in[3];
    const float* kb1  = (const float*)d_in[4];
    const float* kW2x = (const float*)d_in[5];
    const float* kW2h = (const float*)d_in[6];
    const float* kb2  = (const float*)d_in[7];
    const float* kW3x = (const float*)d_in[8];
    const float* kW3h = (const float*)d_in[9];
    const float* kb3  = (const float*)d_in[10];
    const float* kD1w = (const float*)d_in[11];
    const float* kD1b = (const float*)d_in[12];
    const float* kD2w = (const float*)d_in[13];
    const float* kD2b = (const float*)d_in[14];
    const float* iWx  = (const float*)d_in[15];
    const float* iWh  = (const float*)d_in[16];
    const float* ib   = (const float*)d_in[17];
    const float* gWx  = (const float*)d_in[18];
    const float* gWh  = (const float*)d_in[19];
    const float* gb   = (const float*)d_in[20];
    const float* iDw  = (const float*)d_in[21];
    const float* iDb  = (const float*)d_in[22];
    const float* fW   = (const float*)d_in[23];
    const float* fb   = (const float*)d_in[24];
    float* outp = (float*)d_out;

    char* ws = (char*)d_ws;
    const size_t MB16 = (size_t)16384 * 256 * 4;
    float* r1a = (float*)(ws);
    float* r1b = (float*)(ws + MB16);
    float* r2a = (float*)(ws + 2 * MB16);
    float* r2b = (float*)(ws + 3 * MB16);
    size_t off = 4 * MB16;
    float* h1seq = (float*)(ws + off); off += (size_t)16384 * 64 * 4;
    float* h2seq = (float*)(ws + off); off += (size_t)16384 * 128 * 4;
    float* glast = (float*)(ws + off); off += (size_t)256 * 8 * 4;
    unsigned short* w1h = (unsigned short*)(ws + off); off += (size_t)52 * 256 * 32 * 2;
    unsigned short* w1l = (unsigned short*)(ws + off); off += (size_t)52 * 256 * 32 * 2;
    unsigned short* wih = (unsigned short*)(ws + off); off += (size_t)64 * 256 * 32 * 2;
    unsigned short* wil = (unsigned short*)(ws + off); off += (size_t)64 * 256 * 32 * 2;
    unsigned short* w2h = (unsigned short*)(ws + off); off += (size_t)2 * 512 * 32 * 2;
    unsigned short* w2l = (unsigned short*)(ws + off); off += (size_t)2 * 512 * 32 * 2;
    unsigned short* w3h = (unsigned short*)(ws + off); off += (size_t)4 * 256 * 32 * 2;
    unsigned short* w3l = (unsigned short*)(ws + off); off += (size_t)4 * 256 * 32 * 2;
    float* xz2   = r2a;   // spans r2a+r2b after img partials consumed
    float* h3seq = h1seq;

    split_all<<<124, 256, 0, stream>>>(kW1x, iWx, kW2x, kW3x,
                                       w1h, w1l, wih, wil, w2h, w2l, w3h, w3l);
    // xz1 partials: Kt=52, ks=2 -> chunks 26 (even); grid 128x2x2 = 512 blocks
    gemm_rd<<<dim3(128, 2, 2), 256, 0, stream>>>(keypoint, w1h, w1l, kb1, r1a, r1b, 1662, 52, 256);
    // xz_img partials: Kt=64, ks=2 -> chunks 32
    gemm_rd<<<dim3(128, 2, 2), 256, 0, stream>>>(img, wih, wil, ib, r2a, r2b, 2048, 64, 256);
    // LSTM1 (keypoint) + img LSTM with fused GRU (no hsimg round-trip)
    lstm_h64<<<512, 256, 0, stream>>>(256, r1a, r1b, kW1h, h1seq, 0,
                                           r2a, r2b, iWh, nullptr, 1,
                                           gWx, gWh, gb, glast);
    // xz2: Kt=2, ks=1 -> 1 group; N=512 -> grid 128x4x1
    gemm_rd<<<dim3(128, 4, 1), 256, 0, stream>>>(h1seq, w2h, w2l, kb2, xz2, xz2, 64, 2, 512);
    lstm_h128<<<256, 512, 0, stream>>>(xz2, kW2h, h2seq);
    // xz3: Kt=4, ks=2 -> chunks 2 -> G=1
    gemm_rd<<<dim3(128, 2, 2), 256, 0, stream>>>(h2seq, w3h, w3l, kb3, r1a, r1b, 128, 4, 256);
    lstm_h64<<<256, 256, 0, stream>>>(256, r1a, r1b, kW3h, h3seq, 0,
                                           nullptr, nullptr, nullptr, nullptr, 0,
                                           nullptr, nullptr, nullptr, nullptr);
    final_head<<<4, 64, 0, stream>>>(h3seq, glast, kD1w, kD1b, kD2w, kD2b,
                                     iDw, iDb, fW, fb, outp);
    (void)in_sizes; (void)n_in; (void)out_size; (void)ws_size;
}

// Round 9
// 665.803 us; speedup vs baseline: 1.0046x; 1.0046x over previous
//
#include <hip/hip_runtime.h>

// ---------------------------------------------------------------------------
// CombinedModel: 3x relu-LSTM (keypoint) + tanh-LSTM + GRU (img) + heads.
//   r9 KEY change: lstm_h64 was spilling wreg[64] to scratch (VGPR_Count=68
//   < 64 weights + working set) because bare __launch_bounds__(256) let the
//   allocator target high occupancy. Scratch re-read of 64 floats/thread/step
//   in the FMA operand path = the invariant ~3400cyc/step across r2-r8.
//   Fix: __launch_bounds__(256, 2) -> VGPR cap 256, weights stay resident.
//   (lstm_h128 already had (512,2) and never showed in top-5 despite 2x work
//   -- the confirming observation.)
// ---------------------------------------------------------------------------

typedef short bf16x8 __attribute__((ext_vector_type(8)));
typedef float f32x4 __attribute__((ext_vector_type(4)));

__device__ __forceinline__ void block_sync_lds() {
    asm volatile("s_waitcnt lgkmcnt(0)" ::: "memory");   // LDS visible
    __builtin_amdgcn_s_barrier();                        // no vmcnt drain
    __builtin_amdgcn_sched_barrier(0);                   // no hoisting across
}

__device__ __forceinline__ unsigned f2bf(float x) {
    unsigned u = __float_as_uint(x);
    return (u + 0x7FFFu + ((u >> 16) & 1u)) >> 16;   // RNE; inputs finite
}
__device__ __forceinline__ float bf2f(unsigned b) { return __uint_as_float(b << 16); }
__device__ __forceinline__ float sigmoidf_(float x) { return 1.f / (1.f + __expf(-x)); }
__device__ __forceinline__ float tanhf_(float x) {
    float e = __expf(2.f * x);
    return 1.f - 2.f / (e + 1.f);
}

// 2 fp32 -> packed bf16 hi pair + packed bf16 lo pair (HW RNE; validated absmax 0.0).
__device__ __forceinline__ void cvt2(float x0, float x1, unsigned& hp, unsigned& lp) {
    unsigned h;
    asm("v_cvt_pk_bf16_f32 %0, %1, %2" : "=v"(h) : "v"(x0), "v"(x1));
    float a0 = __uint_as_float(h << 16);
    float a1 = __uint_as_float(h & 0xffff0000u);
    unsigned l;
    asm("v_cvt_pk_bf16_f32 %0, %1, %2" : "=v"(l) : "v"(x0 - a0), "v"(x1 - a1));
    hp = h; lp = l;
}

// ---------------------------------------------------------------------------
// Weight pre-split: W[K,N] f32 -> bf16 hi/lo, blocked [kt][n][32].
// ---------------------------------------------------------------------------
template<int K, int N>
__device__ __forceinline__ void split_w(const float* __restrict__ W,
                                        unsigned short* __restrict__ hi,
                                        unsigned short* __restrict__ lo, int item) {
    int kt = item / N;
    int n  = item % N;
    unsigned uh[16], ul[16];
#pragma unroll
    for (int p = 0; p < 16; p++) {
        unsigned h2[2], l2[2];
#pragma unroll
        for (int e = 0; e < 2; e++) {
            int k = kt * 32 + p * 2 + e;
            float x = (k < K) ? W[(size_t)k * N + n] : 0.f;
            unsigned hb = f2bf(x);
            h2[e] = hb;
            l2[e] = f2bf(x - bf2f(hb));
        }
        uh[p] = h2[0] | (h2[1] << 16);
        ul[p] = l2[0] | (l2[1] << 16);
    }
    size_t off = (size_t)(kt * N + n) * 32;
    uint4* dh = (uint4*)(hi + off);
    uint4* dl = (uint4*)(lo + off);
#pragma unroll
    for (int c = 0; c < 4; c++) {
        uint4 v; v.x = uh[c*4]; v.y = uh[c*4+1]; v.z = uh[c*4+2]; v.w = uh[c*4+3];
        dh[c] = v;
        uint4 u; u.x = ul[c*4]; u.y = ul[c*4+1]; u.z = ul[c*4+2]; u.w = ul[c*4+3];
        dl[c] = u;
    }
}

__global__ __launch_bounds__(256) void split_all(
    const float* kW1x, const float* iWx, const float* kW2x, const float* kW3x,
    unsigned short* w1h, unsigned short* w1l, unsigned short* wih, unsigned short* wil,
    unsigned short* w2h, unsigned short* w2l, unsigned short* w3h, unsigned short* w3l) {
    int wid = blockIdx.x * 256 + threadIdx.x;
    if (wid < 13312)       split_w<1662, 256>(kW1x, w1h, w1l, wid);
    else if (wid < 29696)  split_w<2048, 256>(iWx,  wih, wil, wid - 13312);
    else if (wid < 30720)  split_w<64,   512>(kW2x, w2h, w2l, wid - 29696);
    else if (wid < 31744)  split_w<128,  256>(kW3x, w3h, w3l, wid - 30720);
}

// ---------------------------------------------------------------------------
// GEMM: tile 128m x 128n, 4 waves x (128m x 32n), pipelined; barriers drain
// LDS only, so loadB(g+1)/loadA(g+2) stay in flight across them.
// ---------------------------------------------------------------------------
__global__ __launch_bounds__(256, 2) void gemm_rd(
    const float* __restrict__ A, const unsigned short* __restrict__ Bhi,
    const unsigned short* __restrict__ Blo, const float* __restrict__ bias,
    float* __restrict__ out0, float* __restrict__ out1,
    int Kreal, int Kt, int Nfull) {
    const int m0  = blockIdx.x * 128;
    const int n0  = blockIdx.y * 128;
    const int ks  = blockIdx.z;
    const int nks = gridDim.z;
    const int ktChunk = Kt / nks;
    const int kt0 = ks * ktChunk;
    const int G   = (ktChunk + 1) / 2;
    const int tid = threadIdx.x;
    const int lane = tid & 63;
    const int wv   = tid >> 6;
    const int l15  = lane & 15;
    const int q    = lane >> 4;
    const int row  = tid >> 1;
    const int kc   = tid & 1;

    __shared__ unsigned short Ah[2][2][128 * 40], Al[2][2][128 * 40];  // 80 KB

    f32x4 acc[8][2];
#pragma unroll
    for (int i = 0; i < 8; i++)
#pragma unroll
        for (int j = 0; j < 2; j++) acc[i][j] = (f32x4){0.f, 0.f, 0.f, 0.f};

    auto loadA = [&](int g, float* r) {
        int kb = (kt0 + 2 * g + kc) * 32;
        const float* ap = A + (size_t)(m0 + row) * Kreal + kb;
        if (kb + 32 <= Kreal) {
#pragma unroll
            for (int j = 0; j < 16; j++) {
                float2 p = *(const float2*)(ap + 2 * j);
                r[2*j] = p.x; r[2*j+1] = p.y;
            }
        } else {
#pragma unroll
            for (int j = 0; j < 16; j++) {
                int gk = kb + 2 * j;
                r[2*j]   = (gk     < Kreal) ? ap[2*j]   : 0.f;
                r[2*j+1] = (gk + 1 < Kreal) ? ap[2*j+1] : 0.f;
            }
        }
    };
    auto writeA = [&](int buf, const float* r) {
        unsigned ph[16], pl[16];
#pragma unroll
        for (int p = 0; p < 16; p++) cvt2(r[2*p], r[2*p+1], ph[p], pl[p]);
        uint4* dh = (uint4*)&Ah[buf][kc][row * 40];
        uint4* dl = (uint4*)&Al[buf][kc][row * 40];
#pragma unroll
        for (int c = 0; c < 4; c++) {
            uint4 v; v.x = ph[c*4]; v.y = ph[c*4+1]; v.z = ph[c*4+2]; v.w = ph[c*4+3];
            dh[c] = v;
            uint4 u; u.x = pl[c*4]; u.y = pl[c*4+1]; u.z = pl[c*4+2]; u.w = pl[c*4+3];
            dl[c] = u;
        }
    };
    auto loadB = [&](int g, bf16x8* bh, bf16x8* bl) {
#pragma unroll
        for (int sub = 0; sub < 2; sub++)
#pragma unroll
            for (int nt = 0; nt < 2; nt++) {
                size_t boff = ((size_t)(kt0 + 2 * g + sub) * Nfull + n0 + wv * 32 + nt * 16 + l15) * 32 + q * 8;
                bh[sub * 2 + nt] = *(const bf16x8*)(Bhi + boff);
                bl[sub * 2 + nt] = *(const bf16x8*)(Blo + boff);
            }
    };
    auto compute = [&](int buf, const bf16x8* bh, const bf16x8* bl) {
#pragma unroll
        for (int sub = 0; sub < 2; sub++)
#pragma unroll
            for (int mt = 0; mt < 8; mt++) {
                int o = (mt * 16 + l15) * 40 + q * 8;
                bf16x8 ah = *(const bf16x8*)&Ah[buf][sub][o];
                bf16x8 al = *(const bf16x8*)&Al[buf][sub][o];
#pragma unroll
                for (int nt = 0; nt < 2; nt++) {
                    acc[mt][nt] = __builtin_amdgcn_mfma_f32_16x16x32_bf16(ah, bh[sub*2+nt], acc[mt][nt], 0, 0, 0);
                    acc[mt][nt] = __builtin_amdgcn_mfma_f32_16x16x32_bf16(ah, bl[sub*2+nt], acc[mt][nt], 0, 0, 0);
                    acc[mt][nt] = __builtin_amdgcn_mfma_f32_16x16x32_bf16(al, bh[sub*2+nt], acc[mt][nt], 0, 0, 0);
                }
            }
    };

    float  rA[32], rB[32];
    bf16x8 bhA[4], blA[4], bhB[4], blB[4];
    loadA(0, rA);
    writeA(0, rA);
    loadB(0, bhA, blA);
    if (G > 1) loadA(1, rB);
    block_sync_lds();

    for (int g = 0; g < G; g += 2) {
        if (g + 1 < G) loadB(g + 1, bhB, blB);
        if (g + 2 < G) loadA(g + 2, rA);
        compute(0, bhA, blA);
        if (g + 1 < G) writeA(1, rB);
        block_sync_lds();
        if (g + 1 < G) {
            if (g + 2 < G) loadB(g + 2, bhA, blA);
            if (g + 3 < G) loadA(g + 3, rB);
            compute(1, bhB, blB);
            if (g + 2 < G) writeA(0, rA);
            block_sync_lds();
        }
    }

    float* op = (ks == 0) ? out0 : out1;
#pragma unroll
    for (int nt = 0; nt < 2; nt++) {
        int gcol = n0 + wv * 32 + nt * 16 + l15;
        float bv = (ks == 0) ? bias[gcol] : 0.f;
#pragma unroll
        for (int mt = 0; mt < 8; mt++)
#pragma unroll
            for (int r = 0; r < 4; r++) {
                int grow = m0 + mt * 16 + q * 4 + r;
                op[(size_t)grow * Nfull + gcol] = acc[mt][nt][r] + bv;
            }
    }
}

// ---------------------------------------------------------------------------
// LSTM H=64, G=256 (dual-config) — ONE LDS-only barrier per step, depth-2
// xz prefetch. __launch_bounds__(256, 2): VGPR cap 256 so wreg[64] (and the
// fused GRU's wx[64]) stay in REGISTERS, not scratch.
// ---------------------------------------------------------------------------
__global__ __launch_bounds__(256, 2) void lstm_h64(
    int nA,
    const float* __restrict__ xA0, const float* __restrict__ xA1,
    const float* __restrict__ WhA, float* __restrict__ hA, int actA,
    const float* __restrict__ xB0, const float* __restrict__ xB1,
    const float* __restrict__ WhB, float* __restrict__ hB, int actB,
    const float* __restrict__ gWx, const float* __restrict__ gWh,
    const float* __restrict__ gb,  float* __restrict__ glast) {
    int bid = blockIdx.x;
    bool sec = bid >= nA;
    int b = sec ? bid - nA : bid;
    const float* x0 = sec ? xB0 : xA0;
    const float* x1 = sec ? xB1 : xA1;
    const float* Wh = sec ? WhB : WhA;
    float* hout     = sec ? hB  : hA;
    int act         = sec ? actB : actA;
    bool has1  = (x1 != nullptr);
    bool fused = sec && (glast != nullptr);

    int g = threadIdx.x;
    int w = g >> 6;
    int l = g & 63;
    float wreg[64];
#pragma unroll
    for (int k = 0; k < 64; k++) wreg[k] = Wh[k * 256 + g];

    __shared__ alignas(16) float hs4[4][64];   // per-wave private h copy
    __shared__ float za[2][256];               // double-buffered gates
    __shared__ alignas(16) float hseq[64][64]; // h history (fused GRU only)
    hs4[w][l] = 0.f;                           // own wave's row: no sync needed
    float c = 0.f;

    const float* x0r = x0 + (size_t)b * 64 * 256;
    const float* x1r = has1 ? x1 + (size_t)b * 64 * 256 : x0r;
    float* hr = hout ? hout + (size_t)b * 64 * 64 : nullptr;
    bool isc = (g >= 128) && (g < 192);
    // depth-2 prefetch, streams separate
    float c0a = x0r[g],                 c0b = has1 ? x1r[g] : 0.f;
    float n1a = x0r[256 + g],           n1b = has1 ? x1r[256 + g] : 0.f;
    for (int t = 0; t < 64; t++) {
        float n2a = 0.f, n2b = 0.f;
        if (t + 2 < 64) {
            n2a = x0r[(t + 2) * 256 + g];
            if (has1) n2b = x1r[(t + 2) * 256 + g];
        }
        float z0 = c0a + c0b, z1 = 0.f, z2 = 0.f, z3 = 0.f;
#pragma unroll
        for (int kk = 0; kk < 16; kk++) {
            float4 h4 = *(const float4*)&hs4[w][kk * 4];
            z0 = fmaf(h4.x, wreg[kk * 4 + 0], z0);
            z1 = fmaf(h4.y, wreg[kk * 4 + 1], z1);
            z2 = fmaf(h4.z, wreg[kk * 4 + 2], z2);
            z3 = fmaf(h4.w, wreg[kk * 4 + 3], z3);
        }
        float z = (z0 + z1) + (z2 + z3);
        float a;
        if (isc) a = (act == 0) ? fmaxf(z, 0.f) : tanhf_(z);
        else     a = sigmoidf_(z);
        int p = t & 1;
        za[p][g] = a;
        block_sync_lds();
        float iv = za[p][l], fv = za[p][64 + l], cd = za[p][128 + l], ov = za[p][192 + l];
        c = fmaf(fv, c, iv * cd);
        float ca = (act == 0) ? fmaxf(c, 0.f) : tanhf_(c);
        float h = ov * ca;
        hs4[w][l] = h;                        // own copy: next read is wave-local
        if (w == 0) {
            if (hr) hr[t * 64 + l] = h;
            if (fused) hseq[t][l] = h;
        }
        c0a = n1a; c0b = n1b; n1a = n2a; n1b = n2b;
    }

    // ---- fused GRU (img branch), wave 0 only; h-seq from LDS broadcast ----
    if (fused && w == 0) {
        int qq = l;
        int col = (qq < 24) ? qq : 0;
        float wx[64], wh[8];
#pragma unroll
        for (int k = 0; k < 64; k++) wx[k] = gWx[k * 24 + col];
#pragma unroll
        for (int k = 0; k < 8; k++)  wh[k] = gWh[k * 24 + col];
        float b0 = gb[col], b1 = gb[24 + col];
        float hval = 0.f;                     // lanes 0..7 hold h state
        for (int t = 0; t < 64; t++) {
            float s0 = b0, s1 = 0.f, s2 = 0.f, s3 = 0.f;
#pragma unroll
            for (int kk = 0; kk < 16; kk++) {
                float4 h4 = *(const float4*)&hseq[t][kk * 4];
                s0 = fmaf(h4.x, wx[kk * 4 + 0], s0);
                s1 = fmaf(h4.y, wx[kk * 4 + 1], s1);
                s2 = fmaf(h4.z, wx[kk * 4 + 2], s2);
                s3 = fmaf(h4.w, wx[kk * 4 + 3], s3);
            }
            float sx = (s0 + s1) + (s2 + s3);
            float sr = b1;
#pragma unroll
            for (int k = 0; k < 8; k++) sr = fmaf(__shfl(hval, k), wh[k], sr);
            float xzz = __shfl(sx, qq),      rzz = __shfl(sr, qq);
            float xzr = __shfl(sx, 8 + qq),  rzr = __shfl(sr, 8 + qq);
            float xzh = __shfl(sx, 16 + qq), rzh = __shfl(sr, 16 + qq);
            float zz = sigmoidf_(xzz + rzz);
            float rv = sigmoidf_(xzr + rzr);
            float hc = tanhf_(xzh + rv * rzh);
            hval = zz * hval + (1.f - zz) * hc;
        }
        if (qq < 8) glast[b * 8 + qq] = hval;
    }
}

// ---------------------------------------------------------------------------
// LSTM H=128, G=512 — ONE LDS-only barrier per step, depth-2 prefetch.
// ---------------------------------------------------------------------------
__global__ __launch_bounds__(512, 2) void lstm_h128(
    const float* __restrict__ xz, const float* __restrict__ Wh, float* __restrict__ hout) {
    int b = blockIdx.x;
    int g = threadIdx.x;
    int w = g >> 6;
    int l = g & 63;
    float wreg[128];
#pragma unroll
    for (int k = 0; k < 128; k++) wreg[k] = Wh[k * 512 + g];

    __shared__ alignas(16) float hs8[8][128];  // per-wave private h copy
    __shared__ float za[2][512];
    hs8[w][l] = 0.f;
    hs8[w][64 + l] = 0.f;
    float c0 = 0.f, c1 = 0.f;

    const float* xzr = xz + (size_t)b * 64 * 512;
    float* hr = hout + (size_t)b * 64 * 128;
    bool isc = (g >= 256) && (g < 384);
    float cur = xzr[g];
    float nx1 = xzr[512 + g];
    for (int t = 0; t < 64; t++) {
        float nx2 = 0.f;
        if (t + 2 < 64) nx2 = xzr[(t + 2) * 512 + g];
        float z0 = cur, z1 = 0.f, z2 = 0.f, z3 = 0.f;
#pragma unroll
        for (int kk = 0; kk < 32; kk++) {
            float4 h4 = *(const float4*)&hs8[w][kk * 4];
            z0 = fmaf(h4.x, wreg[kk * 4 + 0], z0);
            z1 = fmaf(h4.y, wreg[kk * 4 + 1], z1);
            z2 = fmaf(h4.z, wreg[kk * 4 + 2], z2);
            z3 = fmaf(h4.w, wreg[kk * 4 + 3], z3);
        }
        float z = (z0 + z1) + (z2 + z3);
        float a = isc ? fmaxf(z, 0.f) : sigmoidf_(z);
        int p = t & 1;
        za[p][g] = a;
        block_sync_lds();
        {
            float iv = za[p][l],      fv = za[p][128 + l];
            float cd = za[p][256 + l], ov = za[p][384 + l];
            c0 = fmaf(fv, c0, iv * cd);
            float h = ov * fmaxf(c0, 0.f);
            hs8[w][l] = h;
            if (w == 0) hr[t * 128 + l] = h;
        }
        {
            float iv = za[p][64 + l],  fv = za[p][192 + l];
            float cd = za[p][320 + l], ov = za[p][448 + l];
            c1 = fmaf(fv, c1, iv * cd);
            float h = ov * fmaxf(c1, 0.f);
            hs8[w][64 + l] = h;
            if (w == 0) hr[t * 128 + 64 + l] = h;
        }
        cur = nx1; nx1 = nx2;
    }
}

// ---------------------------------------------------------------------------
// Dense heads + concat + final dense + softmax. 4 blocks x 64 rows.
// (64,1): VGPR cap 512 so the ~180-float working set stays in registers.
// ---------------------------------------------------------------------------
__global__ __launch_bounds__(64, 1) void final_head(
    const float* __restrict__ h3seq, const float* __restrict__ glast,
    const float* __restrict__ kD1w, const float* __restrict__ kD1b,
    const float* __restrict__ kD2w, const float* __restrict__ kD2b,
    const float* __restrict__ iDw,  const float* __restrict__ iDb,
    const float* __restrict__ fW,   const float* __restrict__ fb,
    float* __restrict__ outp) {
    int b = blockIdx.x * 64 + threadIdx.x;
    float h3[64];
#pragma unroll
    for (int k = 0; k < 64; k++) h3[k] = h3seq[((size_t)b * 64 + 63) * 64 + k];
    float d1[64];
#pragma unroll
    for (int j = 0; j < 64; j++) {
        float s = kD1b[j];
#pragma unroll
        for (int k = 0; k < 64; k++) s = fmaf(h3[k], kD1w[k * 64 + j], s);
        d1[j] = fmaxf(s, 0.f);
    }
    float d2[32];
#pragma unroll
    for (int j = 0; j < 32; j++) {
        float s = kD2b[j];
#pragma unroll
        for (int k = 0; k < 64; k++) s = fmaf(d1[k], kD2w[k * 32 + j], s);
        d2[j] = fmaxf(s, 0.f);
    }
    float gi[8];
#pragma unroll
    for (int k = 0; k < 8; k++) gi[k] = glast[b * 8 + k];
    float io[8];
#pragma unroll
    for (int j = 0; j < 8; j++) {
        float s = iDb[j];
#pragma unroll
        for (int k = 0; k < 8; k++) s = fmaf(gi[k], iDw[k * 8 + j], s);
        io[j] = fmaxf(s, 0.f);
    }
    float lg[10];
#pragma unroll
    for (int j = 0; j < 10; j++) {
        float s = fb[j];
#pragma unroll
        for (int k = 0; k < 8; k++)  s = fmaf(io[k], fW[k * 10 + j], s);
#pragma unroll
        for (int k = 0; k < 32; k++) s = fmaf(d2[k], fW[(8 + k) * 10 + j], s);
        lg[j] = s;
    }
    float mx = lg[0];
#pragma unroll
    for (int j = 1; j < 10; j++) mx = fmaxf(mx, lg[j]);
    float den = 0.f, ex[10];
#pragma unroll
    for (int j = 0; j < 10; j++) { ex[j] = __expf(lg[j] - mx); den += ex[j]; }
    float inv = 1.f / den;
#pragma unroll
    for (int j = 0; j < 10; j++) outp[b * 10 + j] = ex[j] * inv;
}

// ---------------------------------------------------------------------------
extern "C" void kernel_launch(void* const* d_in, const int* in_sizes, int n_in,
                              void* d_out, int out_size, void* d_ws, size_t ws_size,
                              hipStream_t stream) {
    const float* keypoint = (const float*)d_in[0];
    const float* img      = (const float*)d_in[1];
    const float* kW1x = (const float*)d_in[2];
    const float* kW1h = (const float*)d_in[3];
    const float* kb1  = (const float*)d_in[4];
    const float* kW2x = (const float*)d_in[5];
    const float* kW2h = (const float*)d_in[6];
    const float* kb2  = (const float*)d_in[7];
    const float* kW3x = (const float*)d_in[8];
    const float* kW3h = (const float*)d_in[9];
    const float* kb3  = (const float*)d_in[10];
    const float* kD1w = (const float*)d_in[11];
    const float* kD1b = (const float*)d_in[12];
    const float* kD2w = (const float*)d_in[13];
    const float* kD2b = (const float*)d_in[14];
    const float* iWx  = (const float*)d_in[15];
    const float* iWh  = (const float*)d_in[16];
    const float* ib   = (const float*)d_in[17];
    const float* gWx  = (const float*)d_in[18];
    const float* gWh  = (const float*)d_in[19];
    const float* gb   = (const float*)d_in[20];
    const float* iDw  = (const float*)d_in[21];
    const float* iDb  = (const float*)d_in[22];
    const float* fW   = (const float*)d_in[23];
    const float* fb   = (const float*)d_in[24];
    float* outp = (float*)d_out;

    char* ws = (char*)d_ws;
    const size_t MB16 = (size_t)16384 * 256 * 4;
    float* r1a = (float*)(ws);
    float* r1b = (float*)(ws + MB16);
    float* r2a = (float*)(ws + 2 * MB16);
    float* r2b = (float*)(ws + 3 * MB16);
    size_t off = 4 * MB16;
    float* h1seq = (float*)(ws + off); off += (size_t)16384 * 64 * 4;
    float* h2seq = (float*)(ws + off); off += (size_t)16384 * 128 * 4;
    float* glast = (float*)(ws + off); off += (size_t)256 * 8 * 4;
    unsigned short* w1h = (unsigned short*)(ws + off); off += (size_t)52 * 256 * 32 * 2;
    unsigned short* w1l = (unsigned short*)(ws + off); off += (size_t)52 * 256 * 32 * 2;
    unsigned short* wih = (unsigned short*)(ws + off); off += (size_t)64 * 256 * 32 * 2;
    unsigned short* wil = (unsigned short*)(ws + off); off += (size_t)64 * 256 * 32 * 2;
    unsigned short* w2h = (unsigned short*)(ws + off); off += (size_t)2 * 512 * 32 * 2;
    unsigned short* w2l = (unsigned short*)(ws + off); off += (size_t)2 * 512 * 32 * 2;
    unsigned short* w3h = (unsigned short*)(ws + off); off += (size_t)4 * 256 * 32 * 2;
    unsigned short* w3l = (unsigned short*)(ws + off); off += (size_t)4 * 256 * 32 * 2;
    float* xz2   = r2a;   // spans r2a+r2b after img partials consumed
    float* h3seq = h1seq;

    split_all<<<124, 256, 0, stream>>>(kW1x, iWx, kW2x, kW3x,
                                       w1h, w1l, wih, wil, w2h, w2l, w3h, w3l);
    // xz1 partials: Kt=52, ks=2 -> chunks 26 (even); grid 128x2x2 = 512 blocks
    gemm_rd<<<dim3(128, 2, 2), 256, 0, stream>>>(keypoint, w1h, w1l, kb1, r1a, r1b, 1662, 52, 256);
    // xz_img partials: Kt=64, ks=2 -> chunks 32
    gemm_rd<<<dim3(128, 2, 2), 256, 0, stream>>>(img, wih, wil, ib, r2a, r2b, 2048, 64, 256);
    // LSTM1 (keypoint) + img LSTM with fused GRU (no hsimg round-trip)
    lstm_h64<<<512, 256, 0, stream>>>(256, r1a, r1b, kW1h, h1seq, 0,
                                           r2a, r2b, iWh, nullptr, 1,
                                           gWx, gWh, gb, glast);
    // xz2: Kt=2, ks=1 -> 1 group; N=512 -> grid 128x4x1
    gemm_rd<<<dim3(128, 4, 1), 256, 0, stream>>>(h1seq, w2h, w2l, kb2, xz2, xz2, 64, 2, 512);
    lstm_h128<<<256, 512, 0, stream>>>(xz2, kW2h, h2seq);
    // xz3: Kt=4, ks=2 -> chunks 2 -> G=1
    gemm_rd<<<dim3(128, 2, 2), 256, 0, stream>>>(h2seq, w3h, w3l, kb3, r1a, r1b, 128, 4, 256);
    lstm_h64<<<256, 256, 0, stream>>>(256, r1a, r1b, kW3h, h3seq, 0,
                                           nullptr, nullptr, nullptr, nullptr, 0,
                                           nullptr, nullptr, nullptr, nullptr);
    final_head<<<4, 64, 0, stream>>>(h3seq, glast, kD1w, kD1b, kD2w, kD2b,
                                     iDw, iDb, fW, fb, outp);
    (void)in_sizes; (void)n_in; (void)out_size; (void)ws_size;
}